// Round 1
// baseline (356.771 us; speedup 1.0000x reference)
//
#include <hip/hip_runtime.h>
#include <math.h>

typedef unsigned short UST;
typedef __attribute__((ext_vector_type(8))) short bf16x8;
typedef __attribute__((ext_vector_type(4))) float f32x4;

#define BB 4
#define LL 1024
#define IND 256
#define DD 512
#define HH 8
#define FFD 2048
#define NT (BB*LL)

__device__ __forceinline__ float bf2f(UST u){ return __uint_as_float(((unsigned)u)<<16); }
__device__ __forceinline__ UST f2bf(float f){
  unsigned u = __float_as_uint(f);
  u += 0x7FFFu + ((u>>16)&1u);
  return (UST)(u>>16);
}
__device__ __forceinline__ float ldF(const void* p, long i, int isf32){
  return isf32 ? ((const float*)p)[i] : bf2f(((const UST*)p)[i]);
}
__device__ __forceinline__ bool ldMask(const void* p, long i, int fm){
  if (fm==0) return ((const int*)p)[i] != 0;
  if (fm==1) return ((const unsigned char*)p)[i] != 0;
  if (fm==2) return ((const UST*)p)[i] != 0;
  return ((const float*)p)[i] != 0.f;
}
__device__ __forceinline__ f32x4 mfma16(bf16x8 a, bf16x8 b, f32x4 c){
  return __builtin_amdgcn_mfma_f32_16x16x32_bf16(a, b, c, 0, 0, 0);
}

// ---------------- dtype detection ----------------
// flags[0]: 0 = floats are bf16, 1 = fp32
// flags[1]: mask repr: 0=int32, 1=uint8, 2=bf16, 3=fp32
__global__ void detect_k(int* flags, const UST* xh, const unsigned int* mw){
  if (threadIdx.x != 0) return;
  int f32 = 0;
  for (int i = 0; i < 128; ++i){
    int e = (xh[i] >> 7) & 0xFF;       // bf16-exponent view; x~N(0,1) => e<=130 if bf16
    if (e >= 140) f32 = 1;             // random fp32 mantissa halves trip this w.h.p.
  }
  int allW01=1, allHalf=1, allWordF=1, allByte=1;
  for (int i = 0; i < 64; ++i){
    unsigned v = mw[i];
    if (v > 1u) allW01 = 0;
    unsigned lo = v & 0xFFFFu, hi = v >> 16;
    if (!((lo==0u||lo==0x3F80u)&&(hi==0u||hi==0x3F80u))) allHalf = 0;
    if (!(v==0u || v==0x3F800000u)) allWordF = 0;
    #pragma unroll
    for (int bs=0; bs<32; bs+=8){ unsigned bt=(v>>bs)&0xFFu; if (bt>1u) allByte=0; }
  }
  int fm;
  if (allW01) fm = 0;
  else if (allHalf) fm = allWordF ? 3 : 2;
  else if (allByte) fm = 1;
  else fm = 0;
  flags[0] = f32;
  flags[1] = fm;
}

// ---------------- bias precompute: [B,L,L] bf16 ----------------
__global__ __launch_bounds__(256) void bias_k(const int* flags, const void* mask,
                                              const void* adj, const void* lsp, UST* biasOut){
  int fF = flags[0], fM = flags[1];
  int row = blockIdx.x;            // b*L + i
  int i = row & (LL-1);
  long base = (long)row * LL;
  int t = threadIdx.x;
  bool mv[4]; int my = 1;
  #pragma unroll
  for (int k = 0; k < 4; ++k){
    mv[k] = ldMask(mask, base + t + k*256, fM);
    my &= mv[k] ? 1 : 0;
  }
  int wa = __all(my);
  __shared__ int sAll[4];
  int w = t >> 6;
  if ((t & 63) == 0) sAll[w] = wa;
  __syncthreads();
  int rowAll = sAll[0] & sAll[1] & sAll[2] & sAll[3];
  float es = expf(ldF(lsp, 0, fF));
  #pragma unroll
  for (int k = 0; k < 4; ++k){
    int j = t + k*256;
    float a = ldF(adj, base + j, fF);
    a = fminf(fmaxf(a, 0.f), 1.f);
    bool eff = mv[k] && !((rowAll != 0) && (j == i));
    float bz = (eff ? -10000.f : 0.f) + es * a;
    biasOut[base + j] = f2bf(bz);
  }
}

// ---------------- generic MFMA GEMM: C[M,N] = A[M,K] * Bw[N,K]^T (+bias,+act,+resid) ----
// aMode: 0 = A is ws bf16, 1 = A dtype per flag. outMode: 0 bf16, 1 fp32, 2 per flag.
__global__ __launch_bounds__(256) void gemm_k(const int* flags,
    const void* A, int aMode, const void* Bw, const void* biasv,
    const float* resid, void* Cout, int outMode,
    int M, int N, int K, int act){
  int fF = flags[0];
  int aF32 = aMode ? fF : 0;
  int bF32 = fF;
  __shared__ UST sA[64*40];
  __shared__ UST sB[64*40];
  int t = threadIdx.x;
  int w = t >> 6, lane = t & 63, l15 = lane & 15, qd = lane >> 4;
  int m0 = blockIdx.x * 64, n0 = blockIdx.y * 64;
  int rowL = t >> 2, colL = (t & 3) * 8;
  f32x4 acc[4];
  #pragma unroll
  for (int i=0;i<4;i++){ acc[i][0]=0.f; acc[i][1]=0.f; acc[i][2]=0.f; acc[i][3]=0.f; }
  long aBase = (long)(m0 + rowL) * K + colL;
  long bBase = (long)(n0 + rowL) * K + colL;
  for (int k0 = 0; k0 < K; k0 += 32){
    int4 av, bv; float a8[8], b8[8];
    if (!aF32) av = *(const int4*)((const UST*)A + aBase + k0);
    else { const float* Af=(const float*)A;
      #pragma unroll
      for (int i=0;i<8;i++) a8[i]=Af[aBase+k0+i]; }
    if (!bF32) bv = *(const int4*)((const UST*)Bw + bBase + k0);
    else { const float* Bf=(const float*)Bw;
      #pragma unroll
      for (int i=0;i<8;i++) b8[i]=Bf[bBase+k0+i]; }
    __syncthreads();
    if (!aF32) *(int4*)&sA[rowL*40+colL] = av;
    else { UST* d=&sA[rowL*40+colL];
      #pragma unroll
      for (int i=0;i<8;i++) d[i]=f2bf(a8[i]); }
    if (!bF32) *(int4*)&sB[rowL*40+colL] = bv;
    else { UST* d=&sB[rowL*40+colL];
      #pragma unroll
      for (int i=0;i<8;i++) d[i]=f2bf(b8[i]); }
    __syncthreads();
    bf16x8 af = *(const bf16x8*)&sA[(w*16 + l15)*40 + qd*8];
    #pragma unroll
    for (int ni=0; ni<4; ++ni){
      bf16x8 bfr = *(const bf16x8*)&sB[(ni*16 + l15)*40 + qd*8];
      acc[ni] = mfma16(af, bfr, acc[ni]);
    }
  }
  int orow = m0 + w*16 + qd*4;
  int outF32 = (outMode==1) || (outMode==2 && fF);
  #pragma unroll
  for (int ni=0; ni<4; ++ni){
    int gc = n0 + ni*16 + l15;
    float bv2 = ldF(biasv, gc, fF);
    #pragma unroll
    for (int r=0; r<4; ++r){
      float c = acc[ni][r] + bv2;
      if (act) c = 0.5f*c*(1.f+erff(c*0.70710678118654752f));
      long oi = (long)(orow + r)*N + gc;
      if (resid) c += resid[oi];
      if (outF32) ((float*)Cout)[oi] = c;
      else ((UST*)Cout)[oi] = f2bf(c);
    }
  }
}

// ---------------- LayerNorm row kernel: fp32 in -> bf16 out ----------------
__global__ __launch_bounds__(256) void ln_k(const int* flags, const float* xin,
    const void* gp, const void* bp, UST* xout){
  int fF = flags[0];
  int row = blockIdx.x, t = threadIdx.x;
  const float* xr = xin + (long)row * DD;
  float v0 = xr[t], v1 = xr[t+256];
  float s = v0+v1, q = v0*v0 + v1*v1;
  #pragma unroll
  for (int off=1; off<64; off<<=1){ s += __shfl_xor(s,off,64); q += __shfl_xor(q,off,64); }
  __shared__ float rs[4], rq[4];
  int w = t>>6;
  if ((t&63)==0){ rs[w]=s; rq[w]=q; }
  __syncthreads();
  float S = rs[0]+rs[1]+rs[2]+rs[3];
  float Q = rq[0]+rq[1]+rq[2]+rq[3];
  float mean = S * (1.f/DD);
  float var  = fmaxf(Q * (1.f/DD) - mean*mean, 0.f);
  float ri = rsqrtf(var + 1e-5f);
  float g0 = ldF(gp, t, fF), b0 = ldF(bp, t, fF);
  float g1 = ldF(gp, t+256, fF), b1 = ldF(bp, t+256, fF);
  xout[(long)row*DD + t]     = f2bf((v0-mean)*ri*g0 + b0);
  xout[(long)row*DD + t+256] = f2bf((v1-mean)*ri*g1 + b1);
}

// ---------------- flash attention: qkv bf16 [N,1536], bias bf16 [B,L,L] -> ctx bf16 [N,512]
__global__ __launch_bounds__(256) void attn_k(const UST* qkv, const UST* bias, UST* ctx){
  int qt = blockIdx.x, bh = blockIdx.y;
  int b = bh >> 3, h = bh & 7;
  int q0 = qt * 64;
  int t = threadIdx.x, w = t>>6, lane = t&63, l15 = lane&15, qd = lane>>4;
  __shared__ UST sK[64*72], sV[64*72], sBias[64*72];
  __shared__ UST sP[4][16*72];
  long qrow = ((long)(b*LL + q0 + w*16 + l15))*1536 + h*64;
  bf16x8 qf0 = *(const bf16x8*)(qkv + qrow + qd*8);
  bf16x8 qf1 = *(const bf16x8*)(qkv + qrow + 32 + qd*8);
  f32x4 o[4]; float mr_[4], lr_[4];
  #pragma unroll
  for (int i=0;i<4;i++){ o[i][0]=0;o[i][1]=0;o[i][2]=0;o[i][3]=0; mr_[i]=-1e30f; lr_[i]=0.f; }
  int rr = t>>2, c4 = (t&3)*16;
  for (int kt = 0; kt < 16; ++kt){
    long kvb = ((long)(b*LL + kt*64 + rr))*1536 + h*64 + c4;
    int4 kv0 = *(const int4*)(qkv + kvb + 512);
    int4 kv1 = *(const int4*)(qkv + kvb + 520);
    int4 vv0 = *(const int4*)(qkv + kvb + 1024);
    int4 vv1 = *(const int4*)(qkv + kvb + 1032);
    long bb = ((long)b<<20) + (long)(q0+rr)*LL + kt*64 + c4;
    int4 bz0 = *(const int4*)(bias + bb);
    int4 bz1 = *(const int4*)(bias + bb + 8);
    __syncthreads();
    *(int4*)&sK[rr*72 + c4]      = kv0;
    *(int4*)&sK[rr*72 + c4 + 8]  = kv1;
    *(int4*)&sBias[rr*72 + c4]     = bz0;
    *(int4*)&sBias[rr*72 + c4 + 8] = bz1;
    union { int4 v; UST u[8]; } u0, u1;
    u0.v = vv0; u1.v = vv1;
    #pragma unroll
    for (int i=0;i<8;i++){ sV[(c4+i)*72 + rr] = u0.u[i]; sV[(c4+8+i)*72 + rr] = u1.u[i]; }
    __syncthreads();
    f32x4 s4[4];
    #pragma unroll
    for (int i=0;i<4;i++){ s4[i][0]=0;s4[i][1]=0;s4[i][2]=0;s4[i][3]=0; }
    #pragma unroll
    for (int ni=0; ni<4; ++ni){
      bf16x8 kf0 = *(const bf16x8*)&sK[(ni*16+l15)*72 + qd*8];
      bf16x8 kf1 = *(const bf16x8*)&sK[(ni*16+l15)*72 + 32 + qd*8];
      s4[ni] = mfma16(qf0, kf0, s4[ni]);
      s4[ni] = mfma16(qf1, kf1, s4[ni]);
    }
    float sv[4][4];
    #pragma unroll
    for (int ni=0; ni<4; ++ni){
      #pragma unroll
      for (int r=0; r<4; ++r){
        int ql = w*16 + qd*4 + r;
        float bzv = bf2f(sBias[ql*72 + ni*16 + l15]);
        sv[ni][r] = s4[ni][r]*0.125f + bzv;
      }
    }
    float alpha[4];
    #pragma unroll
    for (int r=0; r<4; ++r){
      float mcur = fmaxf(fmaxf(sv[0][r],sv[1][r]), fmaxf(sv[2][r],sv[3][r]));
      #pragma unroll
      for (int off=1; off<16; off<<=1) mcur = fmaxf(mcur, __shfl_xor(mcur,off,64));
      float mn = fmaxf(mr_[r], mcur);
      alpha[r] = expf(mr_[r]-mn);
      mr_[r] = mn;
      float psum = 0.f;
      #pragma unroll
      for (int ni=0; ni<4; ++ni){ float p = expf(sv[ni][r]-mn); sv[ni][r]=p; psum += p; }
      #pragma unroll
      for (int off=1; off<16; off<<=1) psum += __shfl_xor(psum,off,64);
      lr_[r] = lr_[r]*alpha[r] + psum;
    }
    #pragma unroll
    for (int dn=0; dn<4; ++dn){
      #pragma unroll
      for (int r=0; r<4; ++r) o[dn][r] *= alpha[r];
    }
    #pragma unroll
    for (int ni=0; ni<4; ++ni){
      #pragma unroll
      for (int r=0; r<4; ++r) sP[w][(qd*4+r)*72 + ni*16 + l15] = f2bf(sv[ni][r]);
    }
    bf16x8 pf0 = *(const bf16x8*)&sP[w][l15*72 + qd*8];
    bf16x8 pf1 = *(const bf16x8*)&sP[w][l15*72 + 32 + qd*8];
    #pragma unroll
    for (int dn=0; dn<4; ++dn){
      bf16x8 vf0 = *(const bf16x8*)&sV[(dn*16+l15)*72 + qd*8];
      bf16x8 vf1 = *(const bf16x8*)&sV[(dn*16+l15)*72 + 32 + qd*8];
      o[dn] = mfma16(pf0, vf0, o[dn]);
      o[dn] = mfma16(pf1, vf1, o[dn]);
    }
  }
  #pragma unroll
  for (int dn=0; dn<4; ++dn){
    #pragma unroll
    for (int r=0; r<4; ++r){
      long oi = ((long)(b*LL + q0 + w*16 + qd*4 + r))*DD + h*64 + dn*16 + l15;
      ctx[oi] = f2bf(o[dn][r] * (1.f/lr_[r]));
    }
  }
}

extern "C" void kernel_launch(void* const* d_in, const int* in_sizes, int n_in,
                              void* d_out, int out_size, void* d_ws, size_t ws_size,
                              hipStream_t stream){
  char* ws = (char*)d_ws;
  int*   flags = (int*)ws;
  UST*   biasC = (UST*)  (ws + 256);
  float* xf    = (float*)(ws + 256 + 8388608L);
  UST*   xn    = (UST*)  (ws + 256 + 8388608L + 8388608L);
  UST*   qkv   = (UST*)  (ws + 256 + 8388608L + 8388608L + 4194304L);
  UST*   ctx   = (UST*)  (ws + 256 + 8388608L + 8388608L + 4194304L + 12582912L);
  float* x2    = (float*)(ws + 256 + 8388608L + 8388608L + 4194304L + 12582912L + 4194304L);
  UST*   hb    = (UST*)  (ws + 256 + 8388608L + 8388608L + 4194304L + 12582912L + 4194304L + 8388608L);

  detect_k<<<1, 64, 0, stream>>>(flags, (const UST*)d_in[0], (const unsigned int*)d_in[1]);
  bias_k<<<BB*LL, 256, 0, stream>>>(flags, d_in[1], d_in[2], d_in[17], biasC);
  // fuse: xf = x * W_fuse^T + b_fuse   (fp32 residual stream)
  gemm_k<<<dim3(NT/64, DD/64), 256, 0, stream>>>(flags, d_in[0], 1, d_in[3], d_in[4],
                                                 nullptr, xf, 1, NT, DD, IND, 0);
  ln_k<<<NT, 256, 0, stream>>>(flags, xf, d_in[9], d_in[10], xn);
  // qkv = xn * in_proj_w^T + in_proj_b  (bf16)
  gemm_k<<<dim3(NT/64, (3*DD)/64), 256, 0, stream>>>(flags, xn, 0, d_in[5], d_in[6],
                                                     nullptr, qkv, 0, NT, 3*DD, DD, 0);
  attn_k<<<dim3(LL/64, BB*HH), 256, 0, stream>>>(qkv, biasC, ctx);
  // x2 = xf + ctx * out_w^T + out_b  (fp32)
  gemm_k<<<dim3(NT/64, DD/64), 256, 0, stream>>>(flags, ctx, 0, d_in[7], d_in[8],
                                                 xf, x2, 1, NT, DD, DD, 0);
  ln_k<<<NT, 256, 0, stream>>>(flags, x2, d_in[11], d_in[12], xn);
  // h = gelu(xn * W1^T + b1)  (bf16)
  gemm_k<<<dim3(NT/64, FFD/64), 256, 0, stream>>>(flags, xn, 0, d_in[13], d_in[14],
                                                  nullptr, hb, 0, NT, FFD, DD, 1);
  // out = x2 + h * W2^T + b2  (dtype per detected flag)
  gemm_k<<<dim3(NT/64, DD/64), 256, 0, stream>>>(flags, hb, 0, d_in[15], d_in[16],
                                                 x2, d_out, 2, NT, DD, FFD, 0);
}

// Round 2
// 308.487 us; speedup vs baseline: 1.1565x; 1.1565x over previous
//
#include <hip/hip_runtime.h>
#include <math.h>

typedef unsigned short UST;
typedef __attribute__((ext_vector_type(8))) short bf16x8;
typedef __attribute__((ext_vector_type(4))) float f32x4;

#define BB 4
#define LL 1024
#define IND 256
#define DD 512
#define HH 8
#define FFD 2048
#define NT (BB*LL)

__device__ __forceinline__ float bf2f(UST u){ return __uint_as_float(((unsigned)u)<<16); }
__device__ __forceinline__ UST f2bf(float f){
  unsigned u = __float_as_uint(f);
  u += 0x7FFFu + ((u>>16)&1u);
  return (UST)(u>>16);
}
__device__ __forceinline__ float ldF(const void* p, long i, int isf32){
  return isf32 ? ((const float*)p)[i] : bf2f(((const UST*)p)[i]);
}
__device__ __forceinline__ bool ldMask(const void* p, long i, int fm){
  if (fm==0) return ((const int*)p)[i] != 0;
  if (fm==1) return ((const unsigned char*)p)[i] != 0;
  if (fm==2) return ((const UST*)p)[i] != 0;
  return ((const float*)p)[i] != 0.f;
}
__device__ __forceinline__ f32x4 mfma16(bf16x8 a, bf16x8 b, f32x4 c){
  return __builtin_amdgcn_mfma_f32_16x16x32_bf16(a, b, c, 0, 0, 0);
}
// async global->LDS, 16B per lane; lds base must be wave-uniform (HW adds lane*16)
__device__ __forceinline__ void gld16(const void* g, void* l){
  __builtin_amdgcn_global_load_lds((const __attribute__((address_space(1))) unsigned int*)g,
                                   (__attribute__((address_space(3))) unsigned int*)l, 16, 0, 0);
}

// ---------------- dtype detection ----------------
// flags[0]: 0 = floats are bf16, 1 = fp32 ; flags[1]: mask repr 0=int32,1=u8,2=bf16,3=fp32
__global__ void detect_k(int* flags, const UST* xh, const unsigned int* mw){
  if (threadIdx.x != 0) return;
  int f32 = 0;
  for (int i = 0; i < 128; ++i){
    int e = (xh[i] >> 7) & 0xFF;
    if (e >= 140) f32 = 1;
  }
  int allW01=1, allHalf=1, allWordF=1, allByte=1;
  for (int i = 0; i < 64; ++i){
    unsigned v = mw[i];
    if (v > 1u) allW01 = 0;
    unsigned lo = v & 0xFFFFu, hi = v >> 16;
    if (!((lo==0u||lo==0x3F80u)&&(hi==0u||hi==0x3F80u))) allHalf = 0;
    if (!(v==0u || v==0x3F800000u)) allWordF = 0;
    #pragma unroll
    for (int bs=0; bs<32; bs+=8){ unsigned bt=(v>>bs)&0xFFu; if (bt>1u) allByte=0; }
  }
  int fm;
  if (allW01) fm = 0;
  else if (allHalf) fm = allWordF ? 3 : 2;
  else if (allByte) fm = 1;
  else fm = 0;
  flags[0] = f32;
  flags[1] = fm;
}

// ---------------- convert inputs to bf16 ws copies ----------------
struct CvtArgs { const void* src[11]; UST* dst[11]; int n[11]; };
__global__ __launch_bounds__(256) void cvt_k(const int* flags, CvtArgs a){
  int ti = blockIdx.y;
  int n = a.n[ti];
  long i8 = ((long)blockIdx.x*256 + threadIdx.x)*8;
  if (i8 >= n) return;
  const void* s = a.src[ti]; UST* d = a.dst[ti];
  if (flags[0]){
    const float4* sf = (const float4*)s;
    float4 a0 = sf[i8>>2], a1 = sf[(i8>>2)+1];
    UST o[8] = { f2bf(a0.x),f2bf(a0.y),f2bf(a0.z),f2bf(a0.w),
                 f2bf(a1.x),f2bf(a1.y),f2bf(a1.z),f2bf(a1.w) };
    *(int4*)(d+i8) = *(const int4*)o;
  } else {
    ((int4*)d)[i8>>3] = ((const int4*)s)[i8>>3];
  }
}

// ---------------- bias precompute: [B,L,L] bf16 ----------------
__global__ __launch_bounds__(256) void bias_k(const int* flags, const void* mask,
                                              const void* adj, const void* lsp, UST* biasOut){
  int fF = flags[0], fM = flags[1];
  int row = blockIdx.x;
  int i = row & (LL-1);
  long base = (long)row * LL;
  int t = threadIdx.x;
  bool mv[4]; int my = 1;
  #pragma unroll
  for (int k = 0; k < 4; ++k){
    mv[k] = ldMask(mask, base + t + k*256, fM);
    my &= mv[k] ? 1 : 0;
  }
  int wa = __all(my);
  __shared__ int sAll[4];
  int w = t >> 6;
  if ((t & 63) == 0) sAll[w] = wa;
  __syncthreads();
  int rowAll = sAll[0] & sAll[1] & sAll[2] & sAll[3];
  float es = expf(ldF(lsp, 0, fF));
  #pragma unroll
  for (int k = 0; k < 4; ++k){
    int j = t + k*256;
    float a = ldF(adj, base + j, fF);
    a = fminf(fmaxf(a, 0.f), 1.f);
    bool eff = mv[k] && !((rowAll != 0) && (j == i));
    float bz = (eff ? -10000.f : 0.f) + es * a;
    biasOut[base + j] = f2bf(bz);
  }
}

// ---------------- m97-style MFMA GEMM ----------------
// C[M,N] = A[M,K] * Bw[N,K]^T + bias (+gelu) (+resid). All operands bf16 in ws.
// Tile 128 x (32*NI); 4 waves as 2x2; per-wave 4 x NI fragments of 16x16.
template<int NI, int ACT, int RES, int OUTMODE>
__global__ __launch_bounds__(256) void gemm2_k(const int* flags,
    const UST* __restrict__ A, const UST* __restrict__ Bw, const UST* __restrict__ bias,
    const float* __restrict__ resid, void* Cout, int M, int N, int K){
  constexpr int TN = 32*NI;
  __shared__ UST sA[128*32];
  __shared__ UST sB[TN*32];
  int t = threadIdx.x, w = t>>6, lane = t&63, l15 = lane&15, qd = lane>>4;
  int m0 = blockIdx.x*128, n0 = blockIdx.y*TN;
  int wm = (w&1)*64, wn = (w>>1)*(NI*16);
  f32x4 acc[4][NI];
  #pragma unroll
  for (int mi=0; mi<4; ++mi)
    #pragma unroll
    for (int ni=0; ni<NI; ++ni){ acc[mi][ni][0]=0;acc[mi][ni][1]=0;acc[mi][ni][2]=0;acc[mi][ni][3]=0; }
  int arow = t>>2, acol = (t&3)*8;
  const UST* aSrc = A + (long)(m0+arow)*K + acol;
  const UST* bSrc = Bw + (long)(n0+arow)*K + acol;
  char* ldsA0 = (char*)sA + (w*64)*16;
  char* ldsA1 = (char*)sA + (256 + w*64)*16;
  char* ldsB0 = (char*)sB + (w*64)*16;
  char* ldsB1 = (char*)sB + (256 + w*64)*16;
  for (int k0 = 0; k0 < K; k0 += 32){
    __syncthreads();
    gld16(aSrc + k0, ldsA0);
    gld16(aSrc + 64*K + k0, ldsA1);
    gld16(bSrc + k0, ldsB0);
    if (NI == 4) gld16(bSrc + 64*K + k0, ldsB1);
    __syncthreads();
    bf16x8 afr[4], bfr[NI];
    #pragma unroll
    for (int mi=0; mi<4; ++mi) afr[mi] = *(const bf16x8*)&sA[(wm + mi*16 + l15)*32 + qd*8];
    #pragma unroll
    for (int ni=0; ni<NI; ++ni) bfr[ni] = *(const bf16x8*)&sB[(wn + ni*16 + l15)*32 + qd*8];
    #pragma unroll
    for (int mi=0; mi<4; ++mi)
      #pragma unroll
      for (int ni=0; ni<NI; ++ni)
        acc[mi][ni] = mfma16(afr[mi], bfr[ni], acc[mi][ni]);
  }
  int outF32 = (OUTMODE==1) || (OUTMODE==2 && flags[0]);
  #pragma unroll
  for (int mi=0; mi<4; ++mi){
    #pragma unroll
    for (int ni=0; ni<NI; ++ni){
      int gc = n0 + wn + ni*16 + l15;
      float bv = bf2f(bias[gc]);
      #pragma unroll
      for (int r=0; r<4; ++r){
        int grow = m0 + wm + mi*16 + qd*4 + r;
        float c = acc[mi][ni][r] + bv;
        if (ACT) c = 0.5f*c*(1.f+erff(c*0.70710678118654752f));
        long oi = (long)grow*N + gc;
        if (RES) c += resid[oi];
        if (outF32) ((float*)Cout)[oi] = c;
        else ((UST*)Cout)[oi] = f2bf(c);
      }
    }
  }
}

// ---------------- LayerNorm row kernel: fp32 in -> bf16 out ----------------
__global__ __launch_bounds__(256) void ln_k(const int* flags, const float* xin,
    const void* gp, const void* bp, UST* xout){
  int fF = flags[0];
  int row = blockIdx.x, t = threadIdx.x;
  const float* xr = xin + (long)row * DD;
  float v0 = xr[t], v1 = xr[t+256];
  float s = v0+v1, q = v0*v0 + v1*v1;
  #pragma unroll
  for (int off=1; off<64; off<<=1){ s += __shfl_xor(s,off,64); q += __shfl_xor(q,off,64); }
  __shared__ float rs[4], rq[4];
  int w = t>>6;
  if ((t&63)==0){ rs[w]=s; rq[w]=q; }
  __syncthreads();
  float S = rs[0]+rs[1]+rs[2]+rs[3];
  float Q = rq[0]+rq[1]+rq[2]+rq[3];
  float mean = S * (1.f/DD);
  float var  = fmaxf(Q * (1.f/DD) - mean*mean, 0.f);
  float ri = rsqrtf(var + 1e-5f);
  float g0 = ldF(gp, t, fF), b0 = ldF(bp, t, fF);
  float g1 = ldF(gp, t+256, fF), b1 = ldF(bp, t+256, fF);
  xout[(long)row*DD + t]     = f2bf((v0-mean)*ri*g0 + b0);
  xout[(long)row*DD + t+256] = f2bf((v1-mean)*ri*g1 + b1);
}

// ---------------- flash attention ----------------
__global__ __launch_bounds__(256) void attn_k(const UST* qkv, const UST* bias, UST* ctx){
  int qt = blockIdx.x, bh = blockIdx.y;
  int b = bh >> 3, h = bh & 7;
  int q0 = qt * 64;
  int t = threadIdx.x, w = t>>6, lane = t&63, l15 = lane&15, qd = lane>>4;
  __shared__ UST sK[64*72], sV[64*72], sBias[64*72];
  __shared__ UST sP[4][16*72];
  long qrow = ((long)(b*LL + q0 + w*16 + l15))*1536 + h*64;
  bf16x8 qf0 = *(const bf16x8*)(qkv + qrow + qd*8);
  bf16x8 qf1 = *(const bf16x8*)(qkv + qrow + 32 + qd*8);
  f32x4 o[4]; float mr_[4], lr_[4];
  #pragma unroll
  for (int i=0;i<4;i++){ o[i][0]=0;o[i][1]=0;o[i][2]=0;o[i][3]=0; mr_[i]=-1e30f; lr_[i]=0.f; }
  int rr = t>>2, c4 = (t&3)*16;
  for (int kt = 0; kt < 16; ++kt){
    long kvb = ((long)(b*LL + kt*64 + rr))*1536 + h*64 + c4;
    int4 kv0 = *(const int4*)(qkv + kvb + 512);
    int4 kv1 = *(const int4*)(qkv + kvb + 520);
    int4 vv0 = *(const int4*)(qkv + kvb + 1024);
    int4 vv1 = *(const int4*)(qkv + kvb + 1032);
    long bb = ((long)b<<20) + (long)(q0+rr)*LL + kt*64 + c4;
    int4 bz0 = *(const int4*)(bias + bb);
    int4 bz1 = *(const int4*)(bias + bb + 8);
    __syncthreads();
    *(int4*)&sK[rr*72 + c4]      = kv0;
    *(int4*)&sK[rr*72 + c4 + 8]  = kv1;
    *(int4*)&sBias[rr*72 + c4]     = bz0;
    *(int4*)&sBias[rr*72 + c4 + 8] = bz1;
    union { int4 v; UST u[8]; } u0, u1;
    u0.v = vv0; u1.v = vv1;
    #pragma unroll
    for (int i=0;i<8;i++){ sV[(c4+i)*72 + rr] = u0.u[i]; sV[(c4+8+i)*72 + rr] = u1.u[i]; }
    __syncthreads();
    f32x4 s4[4];
    #pragma unroll
    for (int i=0;i<4;i++){ s4[i][0]=0;s4[i][1]=0;s4[i][2]=0;s4[i][3]=0; }
    #pragma unroll
    for (int ni=0; ni<4; ++ni){
      bf16x8 kf0 = *(const bf16x8*)&sK[(ni*16+l15)*72 + qd*8];
      bf16x8 kf1 = *(const bf16x8*)&sK[(ni*16+l15)*72 + 32 + qd*8];
      s4[ni] = mfma16(qf0, kf0, s4[ni]);
      s4[ni] = mfma16(qf1, kf1, s4[ni]);
    }
    float sv[4][4];
    #pragma unroll
    for (int ni=0; ni<4; ++ni){
      #pragma unroll
      for (int r=0; r<4; ++r){
        int ql = w*16 + qd*4 + r;
        float bzv = bf2f(sBias[ql*72 + ni*16 + l15]);
        sv[ni][r] = s4[ni][r]*0.125f + bzv;
      }
    }
    float alpha[4];
    #pragma unroll
    for (int r=0; r<4; ++r){
      float mcur = fmaxf(fmaxf(sv[0][r],sv[1][r]), fmaxf(sv[2][r],sv[3][r]));
      #pragma unroll
      for (int off=1; off<16; off<<=1) mcur = fmaxf(mcur, __shfl_xor(mcur,off,64));
      float mn = fmaxf(mr_[r], mcur);
      alpha[r] = expf(mr_[r]-mn);
      mr_[r] = mn;
      float psum = 0.f;
      #pragma unroll
      for (int ni=0; ni<4; ++ni){ float p = expf(sv[ni][r]-mn); sv[ni][r]=p; psum += p; }
      #pragma unroll
      for (int off=1; off<16; off<<=1) psum += __shfl_xor(psum,off,64);
      lr_[r] = lr_[r]*alpha[r] + psum;
    }
    #pragma unroll
    for (int dn=0; dn<4; ++dn){
      #pragma unroll
      for (int r=0; r<4; ++r) o[dn][r] *= alpha[r];
    }
    #pragma unroll
    for (int ni=0; ni<4; ++ni){
      #pragma unroll
      for (int r=0; r<4; ++r) sP[w][(qd*4+r)*72 + ni*16 + l15] = f2bf(sv[ni][r]);
    }
    bf16x8 pf0 = *(const bf16x8*)&sP[w][l15*72 + qd*8];
    bf16x8 pf1 = *(const bf16x8*)&sP[w][l15*72 + 32 + qd*8];
    #pragma unroll
    for (int dn=0; dn<4; ++dn){
      bf16x8 vf0 = *(const bf16x8*)&sV[(dn*16+l15)*72 + qd*8];
      bf16x8 vf1 = *(const bf16x8*)&sV[(dn*16+l15)*72 + 32 + qd*8];
      o[dn] = mfma16(pf0, vf0, o[dn]);
      o[dn] = mfma16(pf1, vf1, o[dn]);
    }
  }
  #pragma unroll
  for (int dn=0; dn<4; ++dn){
    #pragma unroll
    for (int r=0; r<4; ++r){
      long oi = ((long)(b*LL + q0 + w*16 + qd*4 + r))*DD + h*64 + dn*16 + l15;
      ctx[oi] = f2bf(o[dn][r] * (1.f/lr_[r]));
    }
  }
}

extern "C" void kernel_launch(void* const* d_in, const int* in_sizes, int n_in,
                              void* d_out, int out_size, void* d_ws, size_t ws_size,
                              hipStream_t stream){
  char* ws = (char*)d_ws;
  size_t o = 0;
  auto alloc = [&](size_t b){ size_t r = o; o += (b + 255) & ~(size_t)255; return r; };
  int*   flags = (int*)(ws + alloc(256));
  size_t biasOff = alloc(8UL<<20);          // biasC: 8MB (bf16 [B,L,L])
  size_t qkvOff  = alloc(12UL<<20);         // qkv: 12MB
  UST* biasC = (UST*)(ws + biasOff);
  UST* qkv   = (UST*)(ws + qkvOff);
  UST* hb    = (UST*)(ws + biasOff);        // 16MB, aliases biasC+qkv (both dead by ffn1)
  UST* xbf   = (UST*)(ws + alloc(2UL<<20));
  UST* wfuse = (UST*)(ws + alloc(131072*2));
  UST* bfuse = (UST*)(ws + alloc(1024));
  UST* ipw   = (UST*)(ws + alloc(786432*2));
  UST* ipb   = (UST*)(ws + alloc(3072*2));
  UST* outw  = (UST*)(ws + alloc(262144*2));
  UST* outb  = (UST*)(ws + alloc(1024));
  UST* w1    = (UST*)(ws + alloc(1048576*2));
  UST* b1    = (UST*)(ws + alloc(4096*2));
  UST* w2    = (UST*)(ws + alloc(1048576*2));
  UST* b2    = (UST*)(ws + alloc(1024));
  float* xf  = (float*)(ws + alloc((size_t)NT*DD*4));
  UST* xn    = (UST*)(ws + alloc((size_t)NT*DD*2));
  UST* ctx   = (UST*)(ws + alloc((size_t)NT*DD*2));
  float* x2  = (float*)(ws + alloc((size_t)NT*DD*4));

  detect_k<<<1, 64, 0, stream>>>(flags, (const UST*)d_in[0], (const unsigned int*)d_in[1]);

  CvtArgs ca;
  const int srcIdx[11] = {0,3,4,5,6,7,8,13,14,15,16};
  UST* dsts[11] = {xbf,wfuse,bfuse,ipw,ipb,outw,outb,w1,b1,w2,b2};
  const int ns[11] = {NT*IND, DD*IND, DD, 3*DD*DD, 3*DD, DD*DD, DD, FFD*DD, FFD, DD*FFD, DD};
  for (int i=0;i<11;i++){ ca.src[i]=d_in[srcIdx[i]]; ca.dst[i]=dsts[i]; ca.n[i]=ns[i]; }
  cvt_k<<<dim3(512,11), 256, 0, stream>>>(flags, ca);

  bias_k<<<BB*LL, 256, 0, stream>>>(flags, d_in[1], d_in[2], d_in[17], biasC);

  // fuse: xf = x * W_fuse^T + b_fuse   (fp32 residual stream)
  gemm2_k<2,0,0,1><<<dim3(32,8), 256, 0, stream>>>(flags, xbf, wfuse, bfuse, nullptr, xf, NT, DD, IND);
  ln_k<<<NT, 256, 0, stream>>>(flags, xf, d_in[9], d_in[10], xn);
  // qkv = xn * in_proj_w^T + in_proj_b (bf16)
  gemm2_k<4,0,0,0><<<dim3(32,12), 256, 0, stream>>>(flags, xn, ipw, ipb, nullptr, qkv, NT, 3*DD, DD);
  attn_k<<<dim3(LL/64, BB*HH), 256, 0, stream>>>(qkv, biasC, ctx);
  // x2 = xf + ctx * out_w^T + out_b (fp32)
  gemm2_k<2,0,1,1><<<dim3(32,8), 256, 0, stream>>>(flags, ctx, outw, outb, xf, x2, NT, DD, DD);
  ln_k<<<NT, 256, 0, stream>>>(flags, x2, d_in[11], d_in[12], xn);
  // h = gelu(xn * W1^T + b1) (bf16)
  gemm2_k<4,1,0,0><<<dim3(32,16), 256, 0, stream>>>(flags, xn, w1, b1, nullptr, hb, NT, FFD, DD);
  // out = x2 + h * W2^T + b2 (dtype per detected flag)
  gemm2_k<2,0,1,2><<<dim3(32,8), 256, 0, stream>>>(flags, hb, w2, b2, x2, d_out, NT, DD, FFD);
}